// Round 5
// baseline (286.710 us; speedup 1.0000x reference)
//
#include <hip/hip_runtime.h>
#include <hip/hip_bf16.h>

#define S 9216      // 96*96 spatial positions
#define C 256       // channels
#define NCT 8       // column tiles per GEMM block
#define NG  (NCT*8) // kt-steps per block
#define SCH 1152    // s-chunk for rowsum/colmax kernels

typedef __bf16 bf16x8 __attribute__((ext_vector_type(8)));
typedef float f32x4 __attribute__((ext_vector_type(4)));
typedef unsigned short us8 __attribute__((ext_vector_type(8)));

#define GLOAD_LDS16(g, l) __builtin_amdgcn_global_load_lds( \
    (const __attribute__((address_space(1))) void*)(g),     \
    (__attribute__((address_space(3))) void*)(l), 16, 0, 0)

__device__ __forceinline__ float bf2f(unsigned short u) {
    return __uint_as_float(((unsigned)u) << 16);
}
__device__ __forceinline__ unsigned packbf(float a, float b) {
    __hip_bfloat16 x = __float2bfloat16(a), y = __float2bfloat16(b);
    return (unsigned)*reinterpret_cast<unsigned short*>(&x) |
           ((unsigned)*reinterpret_cast<unsigned short*>(&y) << 16);
}
__device__ __forceinline__ unsigned sel4(int idx, unsigned a, unsigned b,
                                         unsigned c, unsigned d) {
    unsigned r = a;
    r = (idx == 1) ? b : r;
    r = (idx == 2) ? c : r;
    r = (idx == 3) ? d : r;
    return r;
}

// ---------------- mean of gt over spatial, per channel ----------------
__global__ __launch_bounds__(256) void k_mean(const float* __restrict__ gt,
                                              float* __restrict__ meanT) {
    const int c = blockIdx.x;
    const float* p = gt + (size_t)c * S;
    float s = 0.f;
    for (int i = threadIdx.x; i < S; i += 256) s += p[i];
    for (int m = 1; m < 64; m <<= 1) s += __shfl_xor(s, m, 64);
    __shared__ float red[4];
    if ((threadIdx.x & 63) == 0) red[threadIdx.x >> 6] = s;
    __syncthreads();
    if (threadIdx.x == 0)
        meanT[c] = (red[0] + red[1] + red[2] + red[3]) * (1.0f / S);
}

// --- center by mean_t, L2-normalize over C, transpose to [S][C] bf16 ---
// One thread per s: per-c-plane loads are 256B fully coalesced across lanes.
__global__ __launch_bounds__(256) void k_norm(const float* __restrict__ img,
                                              const float* __restrict__ gt,
                                              const float* __restrict__ meanT,
                                              __hip_bfloat16* __restrict__ A,
                                              __hip_bfloat16* __restrict__ B) {
    __shared__ float sm[C];
    const int t = threadIdx.x;
    sm[t] = meanT[t];
    __syncthreads();
    const int s = blockIdx.x * 256 + t;
    float si = 0.f, st = 0.f;
    for (int c = 0; c < C; ++c) {
        const float m  = sm[c];
        const float di = img[(size_t)c * S + s] - m;
        const float dt = gt [(size_t)c * S + s] - m;
        si += di * di;
        st += dt * dt;
    }
    const float ri = 1.0f / fmaxf(sqrtf(si), 1e-12f);
    const float rt = 1.0f / fmaxf(sqrtf(st), 1e-12f);
    unsigned* Ao = reinterpret_cast<unsigned*>(A + (size_t)s * C);
    unsigned* Bo = reinterpret_cast<unsigned*>(B + (size_t)s * C);
    for (int c = 0; c < C; c += 2) {
        const float m0 = sm[c], m1 = sm[c + 1];
        const float i0 = img[(size_t)c * S + s] - m0;
        const float i1 = img[(size_t)(c + 1) * S + s] - m1;
        const float t0 = gt [(size_t)c * S + s] - m0;
        const float t1 = gt [(size_t)(c + 1) * S + s] - m1;
        Ao[c >> 1] = packbf(i0 * ri, i1 * ri);
        Bo[c >> 1] = packbf(t0 * rt, t1 * rt);
    }
}

// ---------------- init reduction buffers ----------------
__global__ __launch_bounds__(256) void k_init(float* __restrict__ rowmin,
                                              float* __restrict__ rowsum,
                                              float* __restrict__ colmax) {
    const int i = blockIdx.x * 256 + threadIdx.x;
    if (i < S) {
        rowmin[i] = __uint_as_float(0x7f800000u);  // +inf
        rowsum[i] = 0.f;
        colmax[i] = 0.f;
    }
}

// ---------------- GEMM pass: store raw^T (coalesced) + rowmin ----------------
// A-resident (128 rows, full K=256 in LDS), B streamed double-buffered with
// counted vmcnt. Epilogue: 4x4 lane-transpose across kgrp so each lane holds
// 16 consecutive r -> two adjacent uint4 stores per (n) -> full 128B lines.
__global__ __launch_bounds__(256, 2) void k_gemm_store(const __hip_bfloat16* __restrict__ A,
                                                       const __hip_bfloat16* __restrict__ B,
                                                       float* __restrict__ rowmin,
                                                       __hip_bfloat16* __restrict__ Q) {
    __shared__ alignas(16) __hip_bfloat16 As[128 * 256];      // 64 KB
    __shared__ alignas(16) __hip_bfloat16 Bs[2 * 128 * 32];   // 16 KB
    const int tid  = threadIdx.x;
    const int lane = tid & 63;
    const int wid  = tid >> 6;
    const int wr   = wid >> 1;
    const int wc   = wid & 1;
    // XCD-aware bijective swizzle: 648 = 8 * 81
    const int orig = blockIdx.x;
    const int wg   = (orig & 7) * 81 + (orig >> 3);
    const int rowBase  = (wg / 9) * 128;
    const int colBase0 = (wg % 9) * (NCT * 128);

    const int frow = lane & 15;
    const int kgrp = lane >> 4;

    // ---- prologue: stage A full-K, then B for g=0,1
    {
        const int arow_lo = (lane >> 5);
        const int achunk  = lane & 31;
        #pragma unroll
        for (int j = 0; j < 16; ++j) {
            const int row = wid * 32 + j * 2 + arow_lo;
            const int c   = achunk ^ (row & 7);
            GLOAD_LDS16(A + (size_t)(rowBase + row) * C + c * 8,
                        &As[wid * 8192 + j * 512 + lane * 8]);
        }
    }
    const int brow_lo = lane >> 2;
    const int bchunk  = (lane & 3) ^ ((lane >> 3) & 3);
    #pragma unroll
    for (int g = 0; g < 2; ++g) {
        const int cb = colBase0 + (g >> 3) * 128;
        const int kt = g & 7;
        #pragma unroll
        for (int i = 0; i < 2; ++i) {
            const int row = wid * 16 + i * 64 + brow_lo;
            GLOAD_LDS16(B + (size_t)(cb + row) * C + kt * 32 + bchunk * 8,
                        &Bs[(g & 1) * 4096 + wid * 512 + i * 2048 + lane * 8]);
        }
    }

    const int bswz = (kgrp ^ ((frow >> 1) & 3)) * 8;

    for (int t = 0; t < NCT; ++t) {
        f32x4 acc[4][4] = {};
        #pragma unroll
        for (int kt = 0; kt < 8; ++kt) {
            const int g = t * 8 + kt;
            if (g < NG - 1) asm volatile("s_waitcnt vmcnt(2)" ::: "memory");
            else            asm volatile("s_waitcnt vmcnt(0)" ::: "memory");
            __builtin_amdgcn_s_barrier();

            bf16x8 af[4], bfr[4];
            #pragma unroll
            for (int m = 0; m < 4; ++m) {
                const int row = wr * 64 + m * 16 + frow;
                const int p   = (kt * 4 + kgrp) ^ (frow & 7);
                af[m] = *reinterpret_cast<const bf16x8*>(&As[row * 256 + p * 8]);
            }
            const int bbase = (g & 1) * 4096;
            #pragma unroll
            for (int n = 0; n < 4; ++n) {
                const int row = wc * 64 + n * 16 + frow;
                bfr[n] = *reinterpret_cast<const bf16x8*>(&Bs[bbase + row * 32 + bswz]);
            }
            #pragma unroll
            for (int m = 0; m < 4; ++m)
                #pragma unroll
                for (int n = 0; n < 4; ++n)
                    acc[m][n] = __builtin_amdgcn_mfma_f32_16x16x32_bf16(af[m], bfr[n], acc[m][n], 0, 0, 0);

            __builtin_amdgcn_s_barrier();

            if (g + 2 < NG) {
                const int g2 = g + 2;
                const int cb = colBase0 + (g2 >> 3) * 128;
                const int k2 = g2 & 7;
                #pragma unroll
                for (int i = 0; i < 2; ++i) {
                    const int row = wid * 16 + i * 64 + brow_lo;
                    GLOAD_LDS16(B + (size_t)(cb + row) * C + k2 * 32 + bchunk * 8,
                                &Bs[(g2 & 1) * 4096 + wid * 512 + i * 2048 + lane * 8]);
                }
            }
        }

        // ---- epilogue tile t
        const int colBase = colBase0 + t * 128;
        float vmin[4][4];
        #pragma unroll
        for (int m = 0; m < 4; ++m)
            #pragma unroll
            for (int q = 0; q < 4; ++q) vmin[m][q] = 1e30f;

        #pragma unroll
        for (int n = 0; n < 4; ++n) {
            const int s = colBase + wc * 64 + n * 16 + frow;
            unsigned w[4][2], tt[4][2];
            #pragma unroll
            for (int m = 0; m < 4; ++m) {
                const float r0 = fmaxf(0.5f * (1.0f - acc[m][n][0]), 0.0f);
                const float r1 = fmaxf(0.5f * (1.0f - acc[m][n][1]), 0.0f);
                const float r2 = fmaxf(0.5f * (1.0f - acc[m][n][2]), 0.0f);
                const float r3 = fmaxf(0.5f * (1.0f - acc[m][n][3]), 0.0f);
                vmin[m][0] = fminf(vmin[m][0], r0);
                vmin[m][1] = fminf(vmin[m][1], r1);
                vmin[m][2] = fminf(vmin[m][2], r2);
                vmin[m][3] = fminf(vmin[m][3], r3);
                w[m][0] = packbf(r0, r1);
                w[m][1] = packbf(r2, r3);
            }
            #pragma unroll
            for (int j = 0; j < 4; ++j) { tt[j][0] = w[j][0]; tt[j][1] = w[j][1]; }
            // 4x4 transpose across the 4 kgrp lanes (stride-16 lane groups):
            // after this, tt[j][h] = raw(r = kgrp*16 + j*4 + 2h + e) for this s.
            #pragma unroll
            for (int d = 1; d < 4; ++d) {
                const int src = kgrp ^ d;
                const unsigned s0 = sel4(src, w[0][0], w[1][0], w[2][0], w[3][0]);
                const unsigned s1 = sel4(src, w[0][1], w[1][1], w[2][1], w[3][1]);
                const unsigned r0 = (unsigned)__shfl_xor((int)s0, d * 16, 64);
                const unsigned r1 = (unsigned)__shfl_xor((int)s1, d * 16, 64);
                #pragma unroll
                for (int j = 0; j < 4; ++j) {
                    tt[j][0] = (src == j) ? r0 : tt[j][0];
                    tt[j][1] = (src == j) ? r1 : tt[j][1];
                }
            }
            __hip_bfloat16* dst = Q + (size_t)s * S + rowBase + wr * 64 + kgrp * 16;
            uint4 lo, hi;
            lo.x = tt[0][0]; lo.y = tt[0][1]; lo.z = tt[1][0]; lo.w = tt[1][1];
            hi.x = tt[2][0]; hi.y = tt[2][1]; hi.z = tt[3][0]; hi.w = tt[3][1];
            *reinterpret_cast<uint4*>(dst)     = lo;
            *reinterpret_cast<uint4*>(dst + 8) = hi;
        }

        #pragma unroll
        for (int m = 0; m < 4; ++m)
            #pragma unroll
            for (int q = 0; q < 4; ++q) {
                float v = vmin[m][q];
                v = fminf(v, __shfl_xor(v, 1, 64));
                v = fminf(v, __shfl_xor(v, 2, 64));
                v = fminf(v, __shfl_xor(v, 4, 64));
                v = fminf(v, __shfl_xor(v, 8, 64));
                if (frow == 0) {
                    const int rg = rowBase + wr * 64 + m * 16 + kgrp * 4 + q;
                    atomicMin((unsigned int*)&rowmin[rg], __float_as_uint(v));
                }
            }
    }
}

// ---------------- rowsum: partial sums over s-chunks ----------------
// grid = 144 r-strips x 8 s-chunks = 1152 blocks. Per block: 64 r x 1152 s.
__global__ __launch_bounds__(256) void k_rowsum(const __hip_bfloat16* __restrict__ Q,
                                                const float* __restrict__ rowmin,
                                                float* __restrict__ rowsum) {
    __shared__ float sinv[64];
    __shared__ float srs[64];
    const int t  = threadIdx.x;
    const int r0 = (blockIdx.x >> 3) * 64;
    const int s0 = (blockIdx.x & 7) * SCH;
    if (t < 64) {
        sinv[t] = 1.0f / (rowmin[r0 + t] + 1e-5f);
        srs[t]  = 0.f;
    }
    __syncthreads();
    const int roct = (t & 7) * 8;
    const int ss   = t >> 3;          // 0..31
    float inv8[8];
    #pragma unroll
    for (int j = 0; j < 8; ++j) inv8[j] = sinv[roct + j];
    const __hip_bfloat16* base = Q + r0 + roct;

    float sums[8] = {};
    #pragma unroll 4
    for (int i = 0; i < SCH / 32; ++i) {
        const int s = s0 + ss + i * 32;
        const us8 v = *reinterpret_cast<const us8*>(base + (size_t)s * S);
        #pragma unroll
        for (int j = 0; j < 8; ++j)
            sums[j] += __expf(2.0f - 2.0f * bf2f(v[j]) * inv8[j]);
    }
    #pragma unroll
    for (int j = 0; j < 8; ++j) {
        float x = sums[j];
        x += __shfl_xor(x, 8, 64);
        x += __shfl_xor(x, 16, 64);
        x += __shfl_xor(x, 32, 64);
        if ((t & 63) < 8) atomicAdd(&srs[roct + j], x);
    }
    __syncthreads();
    if (t < 64) atomicAdd(&rowsum[r0 + t], srs[t]);
}

// ---------------- colmax: max over r of w/rowsum ----------------
__global__ __launch_bounds__(256) void k_colmax(const __hip_bfloat16* __restrict__ Q,
                                                const float* __restrict__ rowmin,
                                                const float* __restrict__ rowsum,
                                                float* __restrict__ colmax) {
    __shared__ float sinv[64];
    __shared__ float sirs[64];
    const int t  = threadIdx.x;
    const int r0 = (blockIdx.x >> 3) * 64;
    const int s0 = (blockIdx.x & 7) * SCH;
    if (t < 64) {
        sinv[t] = 1.0f / (rowmin[r0 + t] + 1e-5f);
        sirs[t] = 1.0f / rowsum[r0 + t];
    }
    __syncthreads();
    const int roct = (t & 7) * 8;
    const int ss   = t >> 3;
    float inv8[8], irs8[8];
    #pragma unroll
    for (int j = 0; j < 8; ++j) { inv8[j] = sinv[roct + j]; irs8[j] = sirs[roct + j]; }
    const __hip_bfloat16* base = Q + r0 + roct;

    #pragma unroll 4
    for (int i = 0; i < SCH / 32; ++i) {
        const int s = s0 + ss + i * 32;
        const us8 v = *reinterpret_cast<const us8*>(base + (size_t)s * S);
        float mx = 0.f;
        #pragma unroll
        for (int j = 0; j < 8; ++j)
            mx = fmaxf(mx, __expf(2.0f - 2.0f * bf2f(v[j]) * inv8[j]) * irs8[j]);
        mx = fmaxf(mx, __shfl_xor(mx, 1, 64));
        mx = fmaxf(mx, __shfl_xor(mx, 2, 64));
        mx = fmaxf(mx, __shfl_xor(mx, 4, 64));
        if ((t & 7) == 0)
            atomicMax((unsigned int*)&colmax[s], __float_as_uint(mx));
    }
}

// ---------------- final: loss = -log(mean_s colmax[s]) ----------------
__global__ __launch_bounds__(256) void k_final(const float* __restrict__ colmax,
                                               float* __restrict__ out) {
    float s = 0.f;
    for (int i = threadIdx.x; i < S; i += 256) s += colmax[i];
    for (int m = 1; m < 64; m <<= 1) s += __shfl_xor(s, m, 64);
    __shared__ float red[4];
    if ((threadIdx.x & 63) == 0) red[threadIdx.x >> 6] = s;
    __syncthreads();
    if (threadIdx.x == 0)
        out[0] = -logf((red[0] + red[1] + red[2] + red[3]) * (1.0f / S));
}

extern "C" void kernel_launch(void* const* d_in, const int* in_sizes, int n_in,
                              void* d_out, int out_size, void* d_ws, size_t ws_size,
                              hipStream_t stream) {
    const float* img = (const float*)d_in[0];
    const float* gt  = (const float*)d_in[1];

    float* ws     = (float*)d_ws;
    float* meanT  = ws;                  // 256 f
    float* rowmin = ws + 256;            // S f
    float* rowsum = rowmin + S;          // S f
    float* colmax = rowsum + S;          // S f
    __hip_bfloat16* A = (__hip_bfloat16*)(colmax + S);
    __hip_bfloat16* B = A + (size_t)S * C;
    __hip_bfloat16* Q = B + (size_t)S * C;   // 170 MB (ws proven large enough in r4)
    float* out = (float*)d_out;

    k_mean<<<C, 256, 0, stream>>>(gt, meanT);
    k_norm<<<S / 256, 256, 0, stream>>>(img, gt, meanT, A, B);
    k_init<<<(S + 255) / 256, 256, 0, stream>>>(rowmin, rowsum, colmax);

    k_gemm_store<<<648, 256, 0, stream>>>(A, B, rowmin, Q);
    k_rowsum<<<1152, 256, 0, stream>>>(Q, rowmin, rowsum);
    k_colmax<<<1152, 256, 0, stream>>>(Q, rowmin, rowsum, colmax);

    k_final<<<1, 256, 0, stream>>>(colmax, out);
}